// Round 1
// baseline (771.990 us; speedup 1.0000x reference)
//
#include <hip/hip_runtime.h>
#include <hip/hip_bf16.h>
#include <stdint.h>

// Problem dims (fixed)
#define B_    4
#define S_    1024
#define D_    1024
#define H_    16
#define NTOK  4096   // B*S

typedef __bf16 bf16_t;
typedef bf16_t bf16x8 __attribute__((ext_vector_type(8)));
typedef bf16_t bf16x4 __attribute__((ext_vector_type(4)));
typedef float  f32x4  __attribute__((ext_vector_type(4)));

__device__ __forceinline__ f32x4 mfma16(bf16x8 a, bf16x8 b, f32x4 c) {
  return __builtin_amdgcn_mfma_f32_16x16x32_bf16(a, b, c, 0, 0, 0);
}
__device__ __forceinline__ void gload16(const void* g, void* l) {
  __builtin_amdgcn_global_load_lds((__attribute__((address_space(1))) uint32_t*)g,
                                   (__attribute__((address_space(3))) uint32_t*)l, 16, 0, 0);
}
__device__ __forceinline__ bf16_t to_bf(float x) { return (bf16_t)x; }

// ---------------- fp32 -> bf16 vector convert ----------------
__global__ void cvt_bf16_kernel(const float* __restrict__ src, bf16_t* __restrict__ dst, int n4) {
  int i = blockIdx.x * blockDim.x + threadIdx.x;
  if (i >= n4) return;
  f32x4 v = ((const f32x4*)src)[i];
  bf16x4 o = { to_bf(v[0]), to_bf(v[1]), to_bf(v[2]), to_bf(v[3]) };
  ((bf16x4*)dst)[i] = o;
}

// ---------------- W [in][out] fp32 -> W^T [out][in] bf16 ----------------
__global__ void wT_kernel(const float* __restrict__ W, bf16_t* __restrict__ WT) {
  __shared__ float t[32][33];
  int bx = blockIdx.x * 32, by = blockIdx.y * 32;
  int tx = threadIdx.x, ty = threadIdx.y;  // block (32,8)
#pragma unroll
  for (int i = 0; i < 4; i++) t[ty + 8 * i][tx] = W[(size_t)(by + ty + 8 * i) * 1024 + bx + tx];
  __syncthreads();
#pragma unroll
  for (int i = 0; i < 4; i++)
    WT[(size_t)(bx + ty + 8 * i) * 1024 + by + tx] = to_bf(t[tx][ty + 8 * i]);
}

// ---------------- mask bytes -> bit pack (32 bytes -> 1 uint32) ----------------
__global__ void maskpack_kernel(const uint32_t* __restrict__ m, uint32_t* __restrict__ out) {
  int t = blockIdx.x * blockDim.x + threadIdx.x;  // 131072 words total
  const uint32_t* p = m + (size_t)t * 8;
  uint32_t r = 0;
#pragma unroll
  for (int j = 0; j < 8; j++) {
    uint32_t v = p[j];
    uint32_t nib = (v & 1u) | ((v >> 7) & 2u) | ((v >> 14) & 4u) | ((v >> 21) & 8u);
    r |= nib << (j * 4);
  }
  out[t] = r;
}

// ---------------- 128x128 bf16 GEMM core: C = A * Bm^T (A[M,1024], Bm[N,1024] row-major) ----
__device__ __forceinline__ void gemm128_core(const bf16_t* __restrict__ A,
                                             const bf16_t* __restrict__ Bm,
                                             int m0, int n0,
                                             bf16_t* As, bf16_t* Bs, f32x4 (&acc)[4][4]) {
  int tid = threadIdx.x, w = tid >> 6, lane = tid & 63, l16 = lane & 15, lg = lane >> 4;
  int wr = w >> 1, wc = w & 1;
  f32x4 zv = {0.f, 0.f, 0.f, 0.f};
#pragma unroll
  for (int r = 0; r < 4; r++)
#pragma unroll
    for (int c = 0; c < 4; c++) acc[r][c] = zv;

  for (int kt = 0; kt < 16; kt++) {
    int k0 = kt * 64;
#pragma unroll
    for (int j = 0; j < 4; j++) {
      int e = ((w * 4 + j) << 9) + (lane << 3);
      int row = e >> 6, col = e & 63;
      gload16(A + (size_t)(m0 + row) * 1024 + k0 + col, As + ((w * 4 + j) << 9));
      gload16(Bm + (size_t)(n0 + row) * 1024 + k0 + col, Bs + ((w * 4 + j) << 9));
    }
    __syncthreads();
#pragma unroll
    for (int kk = 0; kk < 2; kk++) {
      bf16x8 av[4], bv[4];
#pragma unroll
      for (int r = 0; r < 4; r++)
        av[r] = *(const bf16x8*)(As + (wr * 64 + r * 16 + l16) * 64 + kk * 32 + lg * 8);
#pragma unroll
      for (int c = 0; c < 4; c++)
        bv[c] = *(const bf16x8*)(Bs + (wc * 64 + c * 16 + l16) * 64 + kk * 32 + lg * 8);
#pragma unroll
      for (int r = 0; r < 4; r++)
#pragma unroll
        for (int c = 0; c < 4; c++) acc[r][c] = mfma16(av[r], bv[c], acc[r][c]);
    }
    __syncthreads();
  }
}

// ---------------- QKV projection GEMM (z selects q/k/v), epilogue scatters to [b,h,s,dk] ----
__global__ __launch_bounds__(256, 2) void qkv_gemm_kernel(
    const bf16_t* __restrict__ qb, const bf16_t* __restrict__ kb, const bf16_t* __restrict__ vb,
    const bf16_t* __restrict__ WqT, const bf16_t* __restrict__ WkT, const bf16_t* __restrict__ WvT,
    const float* __restrict__ bq, const float* __restrict__ bk, const float* __restrict__ bv,
    bf16_t* __restrict__ Qh, bf16_t* __restrict__ Kh, bf16_t* __restrict__ Vh) {
  __shared__ bf16_t As[128 * 64], Bs[128 * 64];
  int z = blockIdx.z;
  const bf16_t* A  = (z == 0) ? qb  : ((z == 1) ? kb  : vb);
  const bf16_t* Bm = (z == 0) ? WqT : ((z == 1) ? WkT : WvT);
  const float* bias = (z == 0) ? bq : ((z == 1) ? bk : bv);
  bf16_t* out = (z == 0) ? Qh : ((z == 1) ? Kh : Vh);
  int m0 = blockIdx.y * 128, n0 = blockIdx.x * 128;
  f32x4 acc[4][4];
  gemm128_core(A, Bm, m0, n0, As, Bs, acc);

  int tid = threadIdx.x, w = tid >> 6, lane = tid & 63, l16 = lane & 15, lg = lane >> 4;
  int wr = w >> 1, wc = w & 1;
#pragma unroll
  for (int c = 0; c < 4; c++) {
    int col = n0 + wc * 64 + c * 16 + l16;  // output feature
    float bb = bias[col];
    int h = col >> 6, dk = col & 63;
#pragma unroll
    for (int r = 0; r < 4; r++) {
#pragma unroll
      for (int i = 0; i < 4; i++) {
        int mrow = m0 + wr * 64 + r * 16 + lg * 4 + i;  // token
        int b = mrow >> 10, s = mrow & 1023;
        out[(((size_t)(b * 16 + h)) * 1024 + s) * 64 + dk] = to_bf(acc[r][c][i] + bb);
      }
    }
  }
}

// ---------------- Vh [bh][s][dv] -> Vt [bh][dv][s] ----------------
__global__ void vT_kernel(const bf16_t* __restrict__ Vh, bf16_t* __restrict__ Vt) {
  __shared__ float t[64][65];
  int bh = blockIdx.z * 16 + blockIdx.y;
  int s0 = blockIdx.x * 64;
  int tx = threadIdx.x & 63, ty = threadIdx.x >> 6;  // 256 threads = 64x4
  const bf16_t* src = Vh + (size_t)bh * 65536;
  bf16_t* dst = Vt + (size_t)bh * 65536;
#pragma unroll
  for (int i = 0; i < 16; i++) t[ty + 4 * i][tx] = (float)src[(size_t)(s0 + ty + 4 * i) * 64 + tx];
  __syncthreads();
#pragma unroll
  for (int i = 0; i < 16; i++)
    dst[(size_t)(ty + 4 * i) * 1024 + s0 + tx] = to_bf(t[tx][ty + 4 * i]);
}

// ---------------- attention: per (b,h, 32-row q tile) ----------------
__global__ __launch_bounds__(256, 2) void attn_kernel(
    const bf16_t* __restrict__ Qh, const bf16_t* __restrict__ Kh, const bf16_t* __restrict__ Vt,
    const uint32_t* __restrict__ mbits, float* __restrict__ attn_out, bf16_t* __restrict__ ctx) {
  constexpr int PSTR = 1032;  // padded LDS row stride (bf16 elems) to spread banks
  __shared__ bf16_t P[32 * PSTR];     // 66 KB: unnormalized probs, bf16
  __shared__ uint32_t mb[1024];       // 4 KB: mask bits for 32 rows x 1024 keys
  __shared__ float redm[128], reds[128];
  int b = blockIdx.z, h = blockIdx.y, q0 = blockIdx.x * 32;
  int tid = threadIdx.x, w = tid >> 6, lane = tid & 63, l16 = lane & 15, lg = lane >> 4;
  int bh = b * 16 + h;

  // stage packed mask (contiguous 4KB)
  ((uint4*)mb)[tid] = ((const uint4*)(mbits + ((size_t)b * 1024 + q0) * 32))[tid];

  // hoist Q fragments (A-layout: row = l16, k = lg*8..+8)
  const bf16_t* Qb = Qh + (size_t)bh * 65536;
  const bf16_t* Kb = Kh + (size_t)bh * 65536;
  bf16x8 qa[2][2];
#pragma unroll
  for (int r = 0; r < 2; r++)
#pragma unroll
    for (int kk = 0; kk < 2; kk++)
      qa[r][kk] = *(const bf16x8*)(Qb + (size_t)(q0 + r * 16 + l16) * 64 + kk * 32 + lg * 8);

  // scores: wave w covers keys [w*256, w*256+256)
  f32x4 zv = {0.f, 0.f, 0.f, 0.f};
  f32x4 sc[2][16];
#pragma unroll
  for (int rt = 0; rt < 2; rt++)
#pragma unroll
    for (int c = 0; c < 16; c++) sc[rt][c] = zv;
  int kcol0 = w * 256;
#pragma unroll 4
  for (int c = 0; c < 16; c++) {
#pragma unroll
    for (int kk = 0; kk < 2; kk++) {
      bf16x8 kv = *(const bf16x8*)(Kb + (size_t)(kcol0 + c * 16 + l16) * 64 + kk * 32 + lg * 8);
      sc[0][c] = mfma16(qa[0][kk], kv, sc[0][c]);
      sc[1][c] = mfma16(qa[1][kk], kv, sc[1][c]);
    }
  }
  __syncthreads();  // mb staged

  // mask + scale + row max (C-layout: row = rt*16 + lg*4 + i, col = kcol0 + c*16 + l16)
  float rmax[2][4], rsum[2][4], rinv[2][4];
#pragma unroll
  for (int rt = 0; rt < 2; rt++)
#pragma unroll
    for (int i = 0; i < 4; i++) rmax[rt][i] = -3e38f;
  const float scale = 0.125f;  // 1/sqrt(64)
#pragma unroll
  for (int rt = 0; rt < 2; rt++) {
#pragma unroll
    for (int j = 0; j < 8; j++) {
      uint32_t wd[4];
#pragma unroll
      for (int i = 0; i < 4; i++) wd[i] = mb[(rt * 16 + lg * 4 + i) * 32 + w * 8 + j];
#pragma unroll
      for (int hf = 0; hf < 2; hf++) {
        int c = j * 2 + hf;
#pragma unroll
        for (int i = 0; i < 4; i++) {
          float s = sc[rt][c][i] * scale;
          if ((wd[i] >> (l16 + hf * 16)) & 1u) s = -1e9f;  // mask==True -> -1e9 (matches ref)
          sc[rt][c][i] = s;
          rmax[rt][i] = fmaxf(rmax[rt][i], s);
        }
      }
    }
  }
#pragma unroll
  for (int m = 1; m < 16; m <<= 1)
#pragma unroll
    for (int rt = 0; rt < 2; rt++)
#pragma unroll
      for (int i = 0; i < 4; i++) rmax[rt][i] = fmaxf(rmax[rt][i], __shfl_xor(rmax[rt][i], m));
  if (l16 == 0) {
#pragma unroll
    for (int rt = 0; rt < 2; rt++)
#pragma unroll
      for (int i = 0; i < 4; i++) redm[w * 32 + rt * 16 + lg * 4 + i] = rmax[rt][i];
  }
  __syncthreads();
#pragma unroll
  for (int rt = 0; rt < 2; rt++)
#pragma unroll
    for (int i = 0; i < 4; i++) {
      int row = rt * 16 + lg * 4 + i;
      rmax[rt][i] = fmaxf(fmaxf(redm[row], redm[32 + row]), fmaxf(redm[64 + row], redm[96 + row]));
      rsum[rt][i] = 0.f;
    }
  // exp + row sum
#pragma unroll
  for (int rt = 0; rt < 2; rt++)
#pragma unroll
    for (int c = 0; c < 16; c++)
#pragma unroll
      for (int i = 0; i < 4; i++) {
        float p = __expf(sc[rt][c][i] - rmax[rt][i]);
        sc[rt][c][i] = p;
        rsum[rt][i] += p;
      }
#pragma unroll
  for (int m = 1; m < 16; m <<= 1)
#pragma unroll
    for (int rt = 0; rt < 2; rt++)
#pragma unroll
      for (int i = 0; i < 4; i++) rsum[rt][i] += __shfl_xor(rsum[rt][i], m);
  if (l16 == 0) {
#pragma unroll
    for (int rt = 0; rt < 2; rt++)
#pragma unroll
      for (int i = 0; i < 4; i++) reds[w * 32 + rt * 16 + lg * 4 + i] = rsum[rt][i];
  }
  __syncthreads();
#pragma unroll
  for (int rt = 0; rt < 2; rt++)
#pragma unroll
    for (int i = 0; i < 4; i++) {
      int row = rt * 16 + lg * 4 + i;
      float gs = reds[row] + reds[32 + row] + reds[64 + row] + reds[96 + row];
      rinv[rt][i] = 1.0f / gs;
    }

  // write normalized attention fp32 to d_out; stash unnormalized P bf16 in LDS
  float* ob = attn_out + ((size_t)bh * 1024 + q0) * 1024;
#pragma unroll
  for (int rt = 0; rt < 2; rt++)
#pragma unroll
    for (int c = 0; c < 16; c++) {
      int colk = kcol0 + c * 16 + l16;
#pragma unroll
      for (int i = 0; i < 4; i++) {
        int row = rt * 16 + lg * 4 + i;
        float p = sc[rt][c][i];
        ob[(size_t)row * 1024 + colk] = p * rinv[rt][i];
        P[row * PSTR + colk] = to_bf(p);
      }
    }
  __syncthreads();

  // PV: wave w computes dv tile [w*16, w*16+16) for all 32 rows
  f32x4 oacc0 = zv, oacc1 = zv;
  const bf16_t* Vb = Vt + ((size_t)bh * 64 + w * 16 + l16) * 1024 + lg * 8;
#pragma unroll 4
  for (int ks = 0; ks < 32; ks++) {
    bf16x8 vv = *(const bf16x8*)(Vb + ks * 32);
    bf16x8 a0 = *(const bf16x8*)(P + l16 * PSTR + ks * 32 + lg * 8);
    bf16x8 a1 = *(const bf16x8*)(P + (16 + l16) * PSTR + ks * 32 + lg * 8);
    oacc0 = mfma16(a0, vv, oacc0);
    oacc1 = mfma16(a1, vv, oacc1);
  }
#pragma unroll
  for (int i = 0; i < 4; i++) {
    int s0r = q0 + lg * 4 + i;
    ctx[((size_t)b * 1024 + s0r) * 1024 + h * 64 + w * 16 + l16] = to_bf(oacc0[i] * rinv[0][i]);
    int s1r = q0 + 16 + lg * 4 + i;
    ctx[((size_t)b * 1024 + s1r) * 1024 + h * 64 + w * 16 + l16] = to_bf(oacc1[i] * rinv[1][i]);
  }
}

// ---------------- output projection GEMM + bias + residual ----------------
__global__ __launch_bounds__(256, 2) void out_gemm_kernel(
    const bf16_t* __restrict__ ctx, const bf16_t* __restrict__ WoT,
    const float* __restrict__ bo, const float* __restrict__ resid, float* __restrict__ preLN) {
  __shared__ bf16_t As[128 * 64], Bs[128 * 64];
  int m0 = blockIdx.y * 128, n0 = blockIdx.x * 128;
  f32x4 acc[4][4];
  gemm128_core(ctx, WoT, m0, n0, As, Bs, acc);
  int tid = threadIdx.x, w = tid >> 6, lane = tid & 63, l16 = lane & 15, lg = lane >> 4;
  int wr = w >> 1, wc = w & 1;
#pragma unroll
  for (int c = 0; c < 4; c++) {
    int col = n0 + wc * 64 + c * 16 + l16;
    float bb = bo[col];
#pragma unroll
    for (int r = 0; r < 4; r++) {
#pragma unroll
      for (int i = 0; i < 4; i++) {
        int mrow = m0 + wr * 64 + r * 16 + lg * 4 + i;
        preLN[(size_t)mrow * 1024 + col] = acc[r][c][i] + bb + resid[(size_t)mrow * 1024 + col];
      }
    }
  }
}

// ---------------- rowwise LayerNorm ----------------
__global__ void ln_kernel(const float* __restrict__ pre, float* __restrict__ out) {
  int row = blockIdx.x, tid = threadIdx.x;  // 256 threads, 4 floats each
  const f32x4 v = ((const f32x4*)(pre + (size_t)row * 1024))[tid];
  float s = v[0] + v[1] + v[2] + v[3];
  float s2 = v[0] * v[0] + v[1] * v[1] + v[2] * v[2] + v[3] * v[3];
#pragma unroll
  for (int m = 32; m > 0; m >>= 1) { s += __shfl_xor(s, m); s2 += __shfl_xor(s2, m); }
  __shared__ float rs[4], rs2[4];
  int w = tid >> 6;
  if ((tid & 63) == 0) { rs[w] = s; rs2[w] = s2; }
  __syncthreads();
  float S = rs[0] + rs[1] + rs[2] + rs[3];
  float S2 = rs2[0] + rs2[1] + rs2[2] + rs2[3];
  float mu = S * (1.f / 1024.f);
  float var = S2 * (1.f / 1024.f) - mu * mu;
  float rstd = rsqrtf(var + 1e-5f);
  f32x4 o = { (v[0] - mu) * rstd, (v[1] - mu) * rstd, (v[2] - mu) * rstd, (v[3] - mu) * rstd };
  ((f32x4*)(out + (size_t)row * 1024))[tid] = o;
}

extern "C" void kernel_launch(void* const* d_in, const int* in_sizes, int n_in,
                              void* d_out, int out_size, void* d_ws, size_t ws_size,
                              hipStream_t stream) {
  const float* q  = (const float*)d_in[0];
  const float* k  = (const float*)d_in[1];
  const float* v  = (const float*)d_in[2];
  const uint8_t* mask = (const uint8_t*)d_in[3];  // numpy bool_, 1 byte/elem
  const float* Wq = (const float*)d_in[4];
  const float* bq = (const float*)d_in[5];
  const float* Wk = (const float*)d_in[6];
  const float* bk = (const float*)d_in[7];
  const float* Wv = (const float*)d_in[8];
  const float* bv = (const float*)d_in[9];
  const float* Wo = (const float*)d_in[10];
  const float* bo = (const float*)d_in[11];

  char* wsp = (char*)d_ws;
  size_t off = 0;
  auto carve = [&](size_t bytes) { void* p = wsp + off; off += (bytes + 255) & ~(size_t)255; return p; };
  bf16_t* qb  = (bf16_t*)carve((size_t)NTOK * 1024 * 2);
  bf16_t* kb  = (bf16_t*)carve((size_t)NTOK * 1024 * 2);
  bf16_t* vb  = (bf16_t*)carve((size_t)NTOK * 1024 * 2);
  bf16_t* WqT = (bf16_t*)carve((size_t)1024 * 1024 * 2);
  bf16_t* WkT = (bf16_t*)carve((size_t)1024 * 1024 * 2);
  bf16_t* WvT = (bf16_t*)carve((size_t)1024 * 1024 * 2);
  bf16_t* WoT = (bf16_t*)carve((size_t)1024 * 1024 * 2);
  bf16_t* Qh  = (bf16_t*)carve((size_t)NTOK * 1024 * 2);
  bf16_t* Kh  = (bf16_t*)carve((size_t)NTOK * 1024 * 2);
  bf16_t* Vh  = (bf16_t*)carve((size_t)NTOK * 1024 * 2);
  bf16_t* Vt  = (bf16_t*)carve((size_t)NTOK * 1024 * 2);
  bf16_t* ctx = (bf16_t*)carve((size_t)NTOK * 1024 * 2);
  uint32_t* mbits = (uint32_t*)carve((size_t)B_ * S_ * 32 * 4);  // 512 KB
  float* preLN = (float*)carve((size_t)NTOK * 1024 * 4);
  (void)ws_size; (void)in_sizes; (void)n_in; (void)out_size;

  float* lnout = (float*)d_out;                          // [B,S,D] fp32
  float* attn_out = (float*)d_out + (size_t)NTOK * 1024; // [B,H,S,S] fp32

  cvt_bf16_kernel<<<4096, 256, 0, stream>>>(q, qb, NTOK * 1024 / 4);
  cvt_bf16_kernel<<<4096, 256, 0, stream>>>(k, kb, NTOK * 1024 / 4);
  cvt_bf16_kernel<<<4096, 256, 0, stream>>>(v, vb, NTOK * 1024 / 4);
  wT_kernel<<<dim3(32, 32), dim3(32, 8), 0, stream>>>(Wq, WqT);
  wT_kernel<<<dim3(32, 32), dim3(32, 8), 0, stream>>>(Wk, WkT);
  wT_kernel<<<dim3(32, 32), dim3(32, 8), 0, stream>>>(Wv, WvT);
  wT_kernel<<<dim3(32, 32), dim3(32, 8), 0, stream>>>(Wo, WoT);
  maskpack_kernel<<<512, 256, 0, stream>>>((const uint32_t*)mask, mbits);
  qkv_gemm_kernel<<<dim3(8, 32, 3), 256, 0, stream>>>(qb, kb, vb, WqT, WkT, WvT,
                                                      bq, bk, bv, Qh, Kh, Vh);
  vT_kernel<<<dim3(16, 16, 4), 256, 0, stream>>>(Vh, Vt);
  attn_kernel<<<dim3(32, 16, 4), 256, 0, stream>>>(Qh, Kh, Vt, mbits, attn_out, ctx);
  out_gemm_kernel<<<dim3(8, 32), 256, 0, stream>>>(ctx, WoT, bo, q, preLN);
  ln_kernel<<<4096, 256, 0, stream>>>(preLN, lnout);
}

// Round 2
// 722.467 us; speedup vs baseline: 1.0685x; 1.0685x over previous
//
#include <hip/hip_runtime.h>
#include <hip/hip_bf16.h>
#include <stdint.h>

// Problem dims (fixed)
#define B_    4
#define S_    1024
#define D_    1024
#define H_    16
#define NTOK  4096   // B*S

typedef __bf16 bf16_t;
typedef bf16_t bf16x8 __attribute__((ext_vector_type(8)));
typedef bf16_t bf16x4 __attribute__((ext_vector_type(4)));
typedef float  f32x4  __attribute__((ext_vector_type(4)));

__device__ __forceinline__ f32x4 mfma16(bf16x8 a, bf16x8 b, f32x4 c) {
  return __builtin_amdgcn_mfma_f32_16x16x32_bf16(a, b, c, 0, 0, 0);
}
__device__ __forceinline__ void gload16(const void* g, void* l) {
  __builtin_amdgcn_global_load_lds((__attribute__((address_space(1))) uint32_t*)g,
                                   (__attribute__((address_space(3))) uint32_t*)l, 16, 0, 0);
}
__device__ __forceinline__ bf16_t to_bf(float x) { return (bf16_t)x; }

// ---------------- fp32 -> bf16 vector convert (z selects q/k/v) ----------------
__global__ void cvt3_kernel(const float* __restrict__ q, const float* __restrict__ k,
                            const float* __restrict__ v, bf16_t* __restrict__ qb,
                            bf16_t* __restrict__ kb, bf16_t* __restrict__ vb) {
  int z = blockIdx.z;
  const float* src = (z == 0) ? q : ((z == 1) ? k : v);
  bf16_t* dst = (z == 0) ? qb : ((z == 1) ? kb : vb);
  int i = blockIdx.x * blockDim.x + threadIdx.x;  // 1M vec4 per tensor
  f32x4 val = ((const f32x4*)src)[i];
  bf16x4 o = { to_bf(val[0]), to_bf(val[1]), to_bf(val[2]), to_bf(val[3]) };
  ((bf16x4*)dst)[i] = o;
}

// ---------------- W [in][out] fp32 -> W^T [out][in] bf16 (z selects Wq/Wk/Wv/Wo) ----------
__global__ void wT4_kernel(const float* __restrict__ Wq, const float* __restrict__ Wk,
                           const float* __restrict__ Wv, const float* __restrict__ Wo,
                           bf16_t* __restrict__ WqT, bf16_t* __restrict__ WkT,
                           bf16_t* __restrict__ WvT, bf16_t* __restrict__ WoT) {
  int z = blockIdx.z;
  const float* W = (z == 0) ? Wq : ((z == 1) ? Wk : ((z == 2) ? Wv : Wo));
  bf16_t* WT = (z == 0) ? WqT : ((z == 1) ? WkT : ((z == 2) ? WvT : WoT));
  __shared__ float t[32][33];
  int bx = blockIdx.x * 32, by = blockIdx.y * 32;
  int tx = threadIdx.x, ty = threadIdx.y;  // block (32,8)
#pragma unroll
  for (int i = 0; i < 4; i++) t[ty + 8 * i][tx] = W[(size_t)(by + ty + 8 * i) * 1024 + bx + tx];
  __syncthreads();
#pragma unroll
  for (int i = 0; i < 4; i++)
    WT[(size_t)(bx + ty + 8 * i) * 1024 + by + tx] = to_bf(t[tx][ty + 8 * i]);
}

// ---------------- mask bytes -> bit pack (32 bytes -> 1 uint32) ----------------
__global__ void maskpack_kernel(const uint32_t* __restrict__ m, uint32_t* __restrict__ out) {
  int t = blockIdx.x * blockDim.x + threadIdx.x;  // 131072 words total
  const uint32_t* p = m + (size_t)t * 8;
  uint32_t r = 0;
#pragma unroll
  for (int j = 0; j < 8; j++) {
    uint32_t v = p[j];
    uint32_t nib = (v & 1u) | ((v >> 7) & 2u) | ((v >> 14) & 4u) | ((v >> 21) & 8u);
    r |= nib << (j * 4);
  }
  out[t] = r;
}

// ---------------- 128x128 bf16 GEMM core: C = A * Bm^T (A[M,1024], Bm[N,1024] row-major) ----
__device__ __forceinline__ void gemm128_core(const bf16_t* __restrict__ A,
                                             const bf16_t* __restrict__ Bm,
                                             int m0, int n0,
                                             bf16_t* As, bf16_t* Bs, f32x4 (&acc)[4][4]) {
  int tid = threadIdx.x, w = tid >> 6, lane = tid & 63, l16 = lane & 15, lg = lane >> 4;
  int wr = w >> 1, wc = w & 1;
  f32x4 zv = {0.f, 0.f, 0.f, 0.f};
#pragma unroll
  for (int r = 0; r < 4; r++)
#pragma unroll
    for (int c = 0; c < 4; c++) acc[r][c] = zv;

  for (int kt = 0; kt < 16; kt++) {
    int k0 = kt * 64;
#pragma unroll
    for (int j = 0; j < 4; j++) {
      int e = ((w * 4 + j) << 9) + (lane << 3);
      int row = e >> 6, col = e & 63;
      gload16(A + (size_t)(m0 + row) * 1024 + k0 + col, As + ((w * 4 + j) << 9));
      gload16(Bm + (size_t)(n0 + row) * 1024 + k0 + col, Bs + ((w * 4 + j) << 9));
    }
    __syncthreads();
#pragma unroll
    for (int kk = 0; kk < 2; kk++) {
      bf16x8 av[4], bv[4];
#pragma unroll
      for (int r = 0; r < 4; r++)
        av[r] = *(const bf16x8*)(As + (wr * 64 + r * 16 + l16) * 64 + kk * 32 + lg * 8);
#pragma unroll
      for (int c = 0; c < 4; c++)
        bv[c] = *(const bf16x8*)(Bs + (wc * 64 + c * 16 + l16) * 64 + kk * 32 + lg * 8);
#pragma unroll
      for (int r = 0; r < 4; r++)
#pragma unroll
        for (int c = 0; c < 4; c++) acc[r][c] = mfma16(av[r], bv[c], acc[r][c]);
    }
    __syncthreads();
  }
}

// ---------------- QKV projection GEMM (z selects q/k/v), epilogue scatters to [b,h,s,dk] ----
__global__ __launch_bounds__(256, 2) void qkv_gemm_kernel(
    const bf16_t* __restrict__ qb, const bf16_t* __restrict__ kb, const bf16_t* __restrict__ vb,
    const bf16_t* __restrict__ WqT, const bf16_t* __restrict__ WkT, const bf16_t* __restrict__ WvT,
    const float* __restrict__ bq, const float* __restrict__ bk, const float* __restrict__ bv,
    bf16_t* __restrict__ Qh, bf16_t* __restrict__ Kh, bf16_t* __restrict__ Vh) {
  __shared__ bf16_t As[128 * 64], Bs[128 * 64];
  int z = blockIdx.z;
  const bf16_t* A  = (z == 0) ? qb  : ((z == 1) ? kb  : vb);
  const bf16_t* Bm = (z == 0) ? WqT : ((z == 1) ? WkT : WvT);
  const float* bias = (z == 0) ? bq : ((z == 1) ? bk : bv);
  bf16_t* out = (z == 0) ? Qh : ((z == 1) ? Kh : Vh);
  int m0 = blockIdx.y * 128, n0 = blockIdx.x * 128;
  f32x4 acc[4][4];
  gemm128_core(A, Bm, m0, n0, As, Bs, acc);

  int tid = threadIdx.x, w = tid >> 6, lane = tid & 63, l16 = lane & 15, lg = lane >> 4;
  int wr = w >> 1, wc = w & 1;
#pragma unroll
  for (int c = 0; c < 4; c++) {
    int col = n0 + wc * 64 + c * 16 + l16;  // output feature
    float bb = bias[col];
    int h = col >> 6, dk = col & 63;
#pragma unroll
    for (int r = 0; r < 4; r++) {
#pragma unroll
      for (int i = 0; i < 4; i++) {
        int mrow = m0 + wr * 64 + r * 16 + lg * 4 + i;  // token
        int b = mrow >> 10, s = mrow & 1023;
        out[(((size_t)(b * 16 + h)) * 1024 + s) * 64 + dk] = to_bf(acc[r][c][i] + bb);
      }
    }
  }
}

// ---------------- Vh [bh][s][dv] -> Vt [bh][dv][s] ----------------
__global__ void vT_kernel(const bf16_t* __restrict__ Vh, bf16_t* __restrict__ Vt) {
  __shared__ float t[64][65];
  int bh = blockIdx.z * 16 + blockIdx.y;
  int s0 = blockIdx.x * 64;
  int tx = threadIdx.x & 63, ty = threadIdx.x >> 6;  // 256 threads = 64x4
  const bf16_t* src = Vh + (size_t)bh * 65536;
  bf16_t* dst = Vt + (size_t)bh * 65536;
#pragma unroll
  for (int i = 0; i < 16; i++) t[ty + 4 * i][tx] = (float)src[(size_t)(s0 + ty + 4 * i) * 64 + tx];
  __syncthreads();
#pragma unroll
  for (int i = 0; i < 16; i++)
    dst[(size_t)(ty + 4 * i) * 1024 + s0 + tx] = to_bf(t[tx][ty + 4 * i]);
}

// ---------------- attention: per (b,h, 32-row q tile), XCD-grouped ----------------
__global__ __launch_bounds__(256, 2) void attn_kernel(
    const bf16_t* __restrict__ Qh, const bf16_t* __restrict__ Kh, const bf16_t* __restrict__ Vt,
    const uint32_t* __restrict__ mbits, float* __restrict__ attn_out, bf16_t* __restrict__ ctx) {
  constexpr int PSTR = 1032;  // padded LDS row stride (bf16 elems)
  __shared__ bf16_t P[32 * PSTR];     // 66 KB: unnormalized probs, bf16
  __shared__ uint32_t mb[1024];       // 4 KB: mask bits for 32 rows x 1024 keys
  __shared__ float redm[128], reds[128], rowinv[32];

  // XCD-aware remap: hardware round-robins linear block id across 8 XCDs.
  // Give each XCD 8 whole (b,h) groups so K/V (256 KB/group) stay in its L2.
  int lin = blockIdx.x + 32 * (blockIdx.y + 16 * blockIdx.z);  // 0..2047
  int xcd = lin & 7;
  int slot = lin >> 3;                 // 0..255 within XCD
  int bh = xcd * 8 + (slot >> 5);      // 0..63
  int q0 = (slot & 31) * 32;
  int b = bh >> 4;

  int tid = threadIdx.x, w = tid >> 6, lane = tid & 63, l16 = lane & 15, lg = lane >> 4;

  // stage packed mask (contiguous 4KB)
  ((uint4*)mb)[tid] = ((const uint4*)(mbits + ((size_t)b * 1024 + q0) * 32))[tid];

  // hoist Q fragments (A-layout: row = l16, k = lg*8..+8)
  const bf16_t* Qb = Qh + (size_t)bh * 65536;
  const bf16_t* Kb = Kh + (size_t)bh * 65536;
  bf16x8 qa[2][2];
#pragma unroll
  for (int r = 0; r < 2; r++)
#pragma unroll
    for (int kk = 0; kk < 2; kk++)
      qa[r][kk] = *(const bf16x8*)(Qb + (size_t)(q0 + r * 16 + l16) * 64 + kk * 32 + lg * 8);

  // scores: wave w covers keys [w*256, w*256+256)
  f32x4 zv = {0.f, 0.f, 0.f, 0.f};
  f32x4 sc[2][16];
#pragma unroll
  for (int rt = 0; rt < 2; rt++)
#pragma unroll
    for (int c = 0; c < 16; c++) sc[rt][c] = zv;
  int kcol0 = w * 256;
#pragma unroll 4
  for (int c = 0; c < 16; c++) {
#pragma unroll
    for (int kk = 0; kk < 2; kk++) {
      bf16x8 kv = *(const bf16x8*)(Kb + (size_t)(kcol0 + c * 16 + l16) * 64 + kk * 32 + lg * 8);
      sc[0][c] = mfma16(qa[0][kk], kv, sc[0][c]);
      sc[1][c] = mfma16(qa[1][kk], kv, sc[1][c]);
    }
  }
  __syncthreads();  // mb staged

  // mask + scale + row max (C-layout: row = rt*16 + lg*4 + i, col = kcol0 + c*16 + l16)
  float rmax[2][4], rsum[2][4], rinv[2][4];
#pragma unroll
  for (int rt = 0; rt < 2; rt++)
#pragma unroll
    for (int i = 0; i < 4; i++) rmax[rt][i] = -3e38f;
  const float scale = 0.125f;  // 1/sqrt(64)
#pragma unroll
  for (int rt = 0; rt < 2; rt++) {
#pragma unroll
    for (int j = 0; j < 8; j++) {
      uint32_t wd[4];
#pragma unroll
      for (int i = 0; i < 4; i++) wd[i] = mb[(rt * 16 + lg * 4 + i) * 32 + w * 8 + j];
#pragma unroll
      for (int hf = 0; hf < 2; hf++) {
        int c = j * 2 + hf;
#pragma unroll
        for (int i = 0; i < 4; i++) {
          float s = sc[rt][c][i] * scale;
          if ((wd[i] >> (l16 + hf * 16)) & 1u) s = -1e9f;  // mask==True -> -1e9
          sc[rt][c][i] = s;
          rmax[rt][i] = fmaxf(rmax[rt][i], s);
        }
      }
    }
  }
#pragma unroll
  for (int m = 1; m < 16; m <<= 1)
#pragma unroll
    for (int rt = 0; rt < 2; rt++)
#pragma unroll
      for (int i = 0; i < 4; i++) rmax[rt][i] = fmaxf(rmax[rt][i], __shfl_xor(rmax[rt][i], m));
  if (l16 == 0) {
#pragma unroll
    for (int rt = 0; rt < 2; rt++)
#pragma unroll
      for (int i = 0; i < 4; i++) redm[w * 32 + rt * 16 + lg * 4 + i] = rmax[rt][i];
  }
  __syncthreads();
#pragma unroll
  for (int rt = 0; rt < 2; rt++)
#pragma unroll
    for (int i = 0; i < 4; i++) {
      int row = rt * 16 + lg * 4 + i;
      rmax[rt][i] = fmaxf(fmaxf(redm[row], redm[32 + row]), fmaxf(redm[64 + row], redm[96 + row]));
      rsum[rt][i] = 0.f;
    }
  // exp + row sum
#pragma unroll
  for (int rt = 0; rt < 2; rt++)
#pragma unroll
    for (int c = 0; c < 16; c++)
#pragma unroll
      for (int i = 0; i < 4; i++) {
        float p = __expf(sc[rt][c][i] - rmax[rt][i]);
        sc[rt][c][i] = p;
        rsum[rt][i] += p;
      }
#pragma unroll
  for (int m = 1; m < 16; m <<= 1)
#pragma unroll
    for (int rt = 0; rt < 2; rt++)
#pragma unroll
      for (int i = 0; i < 4; i++) rsum[rt][i] += __shfl_xor(rsum[rt][i], m);
  if (l16 == 0) {
#pragma unroll
    for (int rt = 0; rt < 2; rt++)
#pragma unroll
      for (int i = 0; i < 4; i++) reds[w * 32 + rt * 16 + lg * 4 + i] = rsum[rt][i];
  }
  __syncthreads();
#pragma unroll
  for (int rt = 0; rt < 2; rt++)
#pragma unroll
    for (int i = 0; i < 4; i++) {
      int row = rt * 16 + lg * 4 + i;
      float gs = reds[row] + reds[32 + row] + reds[64 + row] + reds[96 + row];
      rinv[rt][i] = 1.0f / gs;
    }
  // publish per-row 1/sum for the coalesced writer pass
  if (w == 0 && l16 == 0) {
#pragma unroll
    for (int rt = 0; rt < 2; rt++)
#pragma unroll
      for (int i = 0; i < 4; i++) rowinv[rt * 16 + lg * 4 + i] = rinv[rt][i];
  }

  // stash unnormalized P bf16 in LDS (C-fragment scatter is fine in LDS)
#pragma unroll
  for (int rt = 0; rt < 2; rt++)
#pragma unroll
    for (int c = 0; c < 16; c++) {
      int colk = kcol0 + c * 16 + l16;
#pragma unroll
      for (int i = 0; i < 4; i++) {
        int row = rt * 16 + lg * 4 + i;
        P[row * PSTR + colk] = to_bf(sc[rt][c][i]);
      }
    }
  __syncthreads();

  // PV: wave w computes dv tile [w*16, w*16+16) for all 32 rows
  f32x4 oacc0 = zv, oacc1 = zv;
  const bf16_t* Vb = Vt + ((size_t)bh * 64 + w * 16 + l16) * 1024 + lg * 8;
#pragma unroll 4
  for (int ks = 0; ks < 32; ks++) {
    bf16x8 vv = *(const bf16x8*)(Vb + ks * 32);
    bf16x8 a0 = *(const bf16x8*)(P + l16 * PSTR + ks * 32 + lg * 8);
    bf16x8 a1 = *(const bf16x8*)(P + (16 + l16) * PSTR + ks * 32 + lg * 8);
    oacc0 = mfma16(a0, vv, oacc0);
    oacc1 = mfma16(a1, vv, oacc1);
  }

  // coalesced attention write: wave w owns rows [w*8, w*8+8); 1KB contiguous
  // nontemporal stores (full 64B lines, no RFO, no L2 pollution)
  float* ob = attn_out + ((size_t)bh * 1024 + q0) * 1024;
#pragma unroll
  for (int rr = 0; rr < 8; rr++) {
    int row = w * 8 + rr;
    float inv = rowinv[row];
#pragma unroll
    for (int c = 0; c < 4; c++) {
      int col = c * 256 + lane * 4;
      bf16x4 p4 = *(const bf16x4*)(P + row * PSTR + col);
      f32x4 o = { (float)p4[0] * inv, (float)p4[1] * inv, (float)p4[2] * inv, (float)p4[3] * inv };
      __builtin_nontemporal_store(o, (f32x4*)(ob + (size_t)row * 1024 + col));
    }
  }

  // ctx write (re-read by out_gemm soon; keep cached)
#pragma unroll
  for (int i = 0; i < 4; i++) {
    int s0r = q0 + lg * 4 + i;
    ctx[((size_t)b * 1024 + s0r) * 1024 + (bh & 15) * 64 + w * 16 + l16] = to_bf(oacc0[i] * rinv[0][i]);
    int s1r = q0 + 16 + lg * 4 + i;
    ctx[((size_t)b * 1024 + s1r) * 1024 + (bh & 15) * 64 + w * 16 + l16] = to_bf(oacc1[i] * rinv[1][i]);
  }
}

// ---------------- output projection GEMM + bias + residual ----------------
__global__ __launch_bounds__(256, 2) void out_gemm_kernel(
    const bf16_t* __restrict__ ctx, const bf16_t* __restrict__ WoT,
    const float* __restrict__ bo, const float* __restrict__ resid, float* __restrict__ preLN) {
  __shared__ bf16_t As[128 * 64], Bs[128 * 64];
  int m0 = blockIdx.y * 128, n0 = blockIdx.x * 128;
  f32x4 acc[4][4];
  gemm128_core(ctx, WoT, m0, n0, As, Bs, acc);
  int tid = threadIdx.x, w = tid >> 6, lane = tid & 63, l16 = lane & 15, lg = lane >> 4;
  int wr = w >> 1, wc = w & 1;
#pragma unroll
  for (int c = 0; c < 4; c++) {
    int col = n0 + wc * 64 + c * 16 + l16;
    float bb = bo[col];
#pragma unroll
    for (int r = 0; r < 4; r++) {
#pragma unroll
      for (int i = 0; i < 4; i++) {
        int mrow = m0 + wr * 64 + r * 16 + lg * 4 + i;
        preLN[(size_t)mrow * 1024 + col] = acc[r][c][i] + bb + resid[(size_t)mrow * 1024 + col];
      }
    }
  }
}

// ---------------- rowwise LayerNorm ----------------
__global__ void ln_kernel(const float* __restrict__ pre, float* __restrict__ out) {
  int row = blockIdx.x, tid = threadIdx.x;  // 256 threads, 4 floats each
  const f32x4 v = ((const f32x4*)(pre + (size_t)row * 1024))[tid];
  float s = v[0] + v[1] + v[2] + v[3];
  float s2 = v[0] * v[0] + v[1] * v[1] + v[2] * v[2] + v[3] * v[3];
#pragma unroll
  for (int m = 32; m > 0; m >>= 1) { s += __shfl_xor(s, m); s2 += __shfl_xor(s2, m); }
  __shared__ float rs[4], rs2[4];
  int w = tid >> 6;
  if ((tid & 63) == 0) { rs[w] = s; rs2[w] = s2; }
  __syncthreads();
  float S = rs[0] + rs[1] + rs[2] + rs[3];
  float S2 = rs2[0] + rs2[1] + rs2[2] + rs2[3];
  float mu = S * (1.f / 1024.f);
  float var = S2 * (1.f / 1024.f) - mu * mu;
  float rstd = rsqrtf(var + 1e-5f);
  f32x4 o = { (v[0] - mu) * rstd, (v[1] - mu) * rstd, (v[2] - mu) * rstd, (v[3] - mu) * rstd };
  ((f32x4*)(out + (size_t)row * 1024))[tid] = o;
}

extern "C" void kernel_launch(void* const* d_in, const int* in_sizes, int n_in,
                              void* d_out, int out_size, void* d_ws, size_t ws_size,
                              hipStream_t stream) {
  const float* q  = (const float*)d_in[0];
  const float* k  = (const float*)d_in[1];
  const float* v  = (const float*)d_in[2];
  const uint8_t* mask = (const uint8_t*)d_in[3];  // numpy bool_, 1 byte/elem
  const float* Wq = (const float*)d_in[4];
  const float* bq = (const float*)d_in[5];
  const float* Wk = (const float*)d_in[6];
  const float* bk = (const float*)d_in[7];
  const float* Wv = (const float*)d_in[8];
  const float* bv = (const float*)d_in[9];
  const float* Wo = (const float*)d_in[10];
  const float* bo = (const float*)d_in[11];

  char* wsp = (char*)d_ws;
  size_t off = 0;
  auto carve = [&](size_t bytes) { void* p = wsp + off; off += (bytes + 255) & ~(size_t)255; return p; };
  bf16_t* qb  = (bf16_t*)carve((size_t)NTOK * 1024 * 2);
  bf16_t* kb  = (bf16_t*)carve((size_t)NTOK * 1024 * 2);
  bf16_t* vb  = (bf16_t*)carve((size_t)NTOK * 1024 * 2);
  bf16_t* WqT = (bf16_t*)carve((size_t)1024 * 1024 * 2);
  bf16_t* WkT = (bf16_t*)carve((size_t)1024 * 1024 * 2);
  bf16_t* WvT = (bf16_t*)carve((size_t)1024 * 1024 * 2);
  bf16_t* WoT = (bf16_t*)carve((size_t)1024 * 1024 * 2);
  bf16_t* Qh  = (bf16_t*)carve((size_t)NTOK * 1024 * 2);
  bf16_t* Kh  = (bf16_t*)carve((size_t)NTOK * 1024 * 2);
  bf16_t* Vh  = (bf16_t*)carve((size_t)NTOK * 1024 * 2);
  bf16_t* Vt  = (bf16_t*)carve((size_t)NTOK * 1024 * 2);
  bf16_t* ctx = (bf16_t*)carve((size_t)NTOK * 1024 * 2);
  uint32_t* mbits = (uint32_t*)carve((size_t)B_ * S_ * 32 * 4);  // 512 KB
  float* preLN = (float*)carve((size_t)NTOK * 1024 * 4);
  (void)ws_size; (void)in_sizes; (void)n_in; (void)out_size;

  float* lnout = (float*)d_out;                          // [B,S,D] fp32
  float* attn_out = (float*)d_out + (size_t)NTOK * 1024; // [B,H,S,S] fp32

  cvt3_kernel<<<dim3(4096, 1, 3), 256, 0, stream>>>(q, k, v, qb, kb, vb);
  wT4_kernel<<<dim3(32, 32, 4), dim3(32, 8), 0, stream>>>(Wq, Wk, Wv, Wo, WqT, WkT, WvT, WoT);
  maskpack_kernel<<<512, 256, 0, stream>>>((const uint32_t*)mask, mbits);
  qkv_gemm_kernel<<<dim3(8, 32, 3), 256, 0, stream>>>(qb, kb, vb, WqT, WkT, WvT,
                                                      bq, bk, bv, Qh, Kh, Vh);
  vT_kernel<<<dim3(16, 16, 4), 256, 0, stream>>>(Vh, Vt);
  attn_kernel<<<dim3(32, 16, 4), 256, 0, stream>>>(Qh, Kh, Vt, mbits, attn_out, ctx);
  out_gemm_kernel<<<dim3(8, 32), 256, 0, stream>>>(ctx, WoT, bo, q, preLN);
  ln_kernel<<<4096, 256, 0, stream>>>(preLN, lnout);
}

// Round 3
// 720.098 us; speedup vs baseline: 1.0721x; 1.0033x over previous
//
#include <hip/hip_runtime.h>
#include <hip/hip_bf16.h>
#include <stdint.h>

// Problem dims (fixed)
#define B_    4
#define S_    1024
#define D_    1024
#define H_    16
#define NTOK  4096   // B*S

typedef __bf16 bf16_t;
typedef bf16_t bf16x8 __attribute__((ext_vector_type(8)));
typedef bf16_t bf16x4 __attribute__((ext_vector_type(4)));
typedef float  f32x4  __attribute__((ext_vector_type(4)));

__device__ __forceinline__ f32x4 mfma16(bf16x8 a, bf16x8 b, f32x4 c) {
  return __builtin_amdgcn_mfma_f32_16x16x32_bf16(a, b, c, 0, 0, 0);
}
__device__ __forceinline__ void gload16(const void* g, void* l) {
  __builtin_amdgcn_global_load_lds((__attribute__((address_space(1))) uint32_t*)g,
                                   (__attribute__((address_space(3))) uint32_t*)l, 16, 0, 0);
}
__device__ __forceinline__ bf16_t to_bf(float x) { return (bf16_t)x; }

// streaming 16B store: no-allocate / write-through cache policy (sc0 sc1 nt)
__device__ __forceinline__ void stream_store16(void* p, f32x4 v) {
  asm volatile("global_store_dwordx4 %0, %1, off sc0 sc1 nt" :: "v"(p), "v"(v) : "memory");
}

// ---------------- fp32 -> bf16 vector convert (z selects q/k/v) ----------------
__global__ void cvt3_kernel(const float* __restrict__ q, const float* __restrict__ k,
                            const float* __restrict__ v, bf16_t* __restrict__ qb,
                            bf16_t* __restrict__ kb, bf16_t* __restrict__ vb) {
  int z = blockIdx.z;
  const float* src = (z == 0) ? q : ((z == 1) ? k : v);
  bf16_t* dst = (z == 0) ? qb : ((z == 1) ? kb : vb);
  int i = blockIdx.x * blockDim.x + threadIdx.x;  // 1M vec4 per tensor
  f32x4 val = ((const f32x4*)src)[i];
  bf16x4 o = { to_bf(val[0]), to_bf(val[1]), to_bf(val[2]), to_bf(val[3]) };
  ((bf16x4*)dst)[i] = o;
}

// ---------------- W [in][out] fp32 -> W^T [out][in] bf16 (z selects Wq/Wk/Wv/Wo) ----------
__global__ void wT4_kernel(const float* __restrict__ Wq, const float* __restrict__ Wk,
                           const float* __restrict__ Wv, const float* __restrict__ Wo,
                           bf16_t* __restrict__ WqT, bf16_t* __restrict__ WkT,
                           bf16_t* __restrict__ WvT, bf16_t* __restrict__ WoT) {
  int z = blockIdx.z;
  const float* W = (z == 0) ? Wq : ((z == 1) ? Wk : ((z == 2) ? Wv : Wo));
  bf16_t* WT = (z == 0) ? WqT : ((z == 1) ? WkT : ((z == 2) ? WvT : WoT));
  __shared__ float t[32][33];
  int bx = blockIdx.x * 32, by = blockIdx.y * 32;
  int tx = threadIdx.x, ty = threadIdx.y;  // block (32,8)
#pragma unroll
  for (int i = 0; i < 4; i++) t[ty + 8 * i][tx] = W[(size_t)(by + ty + 8 * i) * 1024 + bx + tx];
  __syncthreads();
#pragma unroll
  for (int i = 0; i < 4; i++)
    WT[(size_t)(bx + ty + 8 * i) * 1024 + by + tx] = to_bf(t[tx][ty + 8 * i]);
}

// ---------------- mask bytes -> bit pack (32 bytes -> 1 uint32) ----------------
__global__ void maskpack_kernel(const uint32_t* __restrict__ m, uint32_t* __restrict__ out) {
  int t = blockIdx.x * blockDim.x + threadIdx.x;  // 131072 words total
  const uint32_t* p = m + (size_t)t * 8;
  uint32_t r = 0;
#pragma unroll
  for (int j = 0; j < 8; j++) {
    uint32_t v = p[j];
    uint32_t nib = (v & 1u) | ((v >> 7) & 2u) | ((v >> 14) & 4u) | ((v >> 21) & 8u);
    r |= nib << (j * 4);
  }
  out[t] = r;
}

// ---------------- 128x128 bf16 GEMM core: C = A * Bm^T (A[M,1024], Bm[N,1024] row-major) ----
__device__ __forceinline__ void gemm128_core(const bf16_t* __restrict__ A,
                                             const bf16_t* __restrict__ Bm,
                                             int m0, int n0,
                                             bf16_t* As, bf16_t* Bs, f32x4 (&acc)[4][4]) {
  int tid = threadIdx.x, w = tid >> 6, lane = tid & 63, l16 = lane & 15, lg = lane >> 4;
  int wr = w >> 1, wc = w & 1;
  f32x4 zv = {0.f, 0.f, 0.f, 0.f};
#pragma unroll
  for (int r = 0; r < 4; r++)
#pragma unroll
    for (int c = 0; c < 4; c++) acc[r][c] = zv;

  for (int kt = 0; kt < 16; kt++) {
    int k0 = kt * 64;
#pragma unroll
    for (int j = 0; j < 4; j++) {
      int e = ((w * 4 + j) << 9) + (lane << 3);
      int row = e >> 6, col = e & 63;
      gload16(A + (size_t)(m0 + row) * 1024 + k0 + col, As + ((w * 4 + j) << 9));
      gload16(Bm + (size_t)(n0 + row) * 1024 + k0 + col, Bs + ((w * 4 + j) << 9));
    }
    __syncthreads();
#pragma unroll
    for (int kk = 0; kk < 2; kk++) {
      bf16x8 av[4], bv[4];
#pragma unroll
      for (int r = 0; r < 4; r++)
        av[r] = *(const bf16x8*)(As + (wr * 64 + r * 16 + l16) * 64 + kk * 32 + lg * 8);
#pragma unroll
      for (int c = 0; c < 4; c++)
        bv[c] = *(const bf16x8*)(Bs + (wc * 64 + c * 16 + l16) * 64 + kk * 32 + lg * 8);
#pragma unroll
      for (int r = 0; r < 4; r++)
#pragma unroll
        for (int c = 0; c < 4; c++) acc[r][c] = mfma16(av[r], bv[c], acc[r][c]);
    }
    __syncthreads();
  }
}

// ---------------- QKV projection GEMM (z selects q/k/v), epilogue scatters to [b,h,s,dk] ----
__global__ __launch_bounds__(256, 2) void qkv_gemm_kernel(
    const bf16_t* __restrict__ qb, const bf16_t* __restrict__ kb, const bf16_t* __restrict__ vb,
    const bf16_t* __restrict__ WqT, const bf16_t* __restrict__ WkT, const bf16_t* __restrict__ WvT,
    const float* __restrict__ bq, const float* __restrict__ bk, const float* __restrict__ bv,
    bf16_t* __restrict__ Qh, bf16_t* __restrict__ Kh, bf16_t* __restrict__ Vh) {
  __shared__ bf16_t As[128 * 64], Bs[128 * 64];
  int z = blockIdx.z;
  const bf16_t* A  = (z == 0) ? qb  : ((z == 1) ? kb  : vb);
  const bf16_t* Bm = (z == 0) ? WqT : ((z == 1) ? WkT : WvT);
  const float* bias = (z == 0) ? bq : ((z == 1) ? bk : bv);
  bf16_t* out = (z == 0) ? Qh : ((z == 1) ? Kh : Vh);
  int m0 = blockIdx.y * 128, n0 = blockIdx.x * 128;
  f32x4 acc[4][4];
  gemm128_core(A, Bm, m0, n0, As, Bs, acc);

  int tid = threadIdx.x, w = tid >> 6, lane = tid & 63, l16 = lane & 15, lg = lane >> 4;
  int wr = w >> 1, wc = w & 1;
#pragma unroll
  for (int c = 0; c < 4; c++) {
    int col = n0 + wc * 64 + c * 16 + l16;  // output feature
    float bb = bias[col];
    int h = col >> 6, dk = col & 63;
#pragma unroll
    for (int r = 0; r < 4; r++) {
#pragma unroll
      for (int i = 0; i < 4; i++) {
        int mrow = m0 + wr * 64 + r * 16 + lg * 4 + i;  // token
        int b = mrow >> 10, s = mrow & 1023;
        out[(((size_t)(b * 16 + h)) * 1024 + s) * 64 + dk] = to_bf(acc[r][c][i] + bb);
      }
    }
  }
}

// ---------------- Vh [bh][s][dv] -> Vt [bh][dv][s] ----------------
__global__ void vT_kernel(const bf16_t* __restrict__ Vh, bf16_t* __restrict__ Vt) {
  __shared__ float t[64][65];
  int bh = blockIdx.z * 16 + blockIdx.y;
  int s0 = blockIdx.x * 64;
  int tx = threadIdx.x & 63, ty = threadIdx.x >> 6;  // 256 threads = 64x4
  const bf16_t* src = Vh + (size_t)bh * 65536;
  bf16_t* dst = Vt + (size_t)bh * 65536;
#pragma unroll
  for (int i = 0; i < 16; i++) t[ty + 4 * i][tx] = (float)src[(size_t)(s0 + ty + 4 * i) * 64 + tx];
  __syncthreads();
#pragma unroll
  for (int i = 0; i < 16; i++)
    dst[(size_t)(ty + 4 * i) * 1024 + s0 + tx] = to_bf(t[tx][ty + 4 * i]);
}

// ---------------- attention: per (b,h, 32-row q tile), XCD-grouped ----------------
__global__ __launch_bounds__(256, 2) void attn_kernel(
    const bf16_t* __restrict__ Qh, const bf16_t* __restrict__ Kh, const bf16_t* __restrict__ Vt,
    const uint32_t* __restrict__ mbits, float* __restrict__ attn_out, bf16_t* __restrict__ ctx) {
  constexpr int PSTR = 1032;  // padded LDS row stride (bf16 elems)
  __shared__ bf16_t P[32 * PSTR];     // 66 KB: unnormalized probs, bf16
  __shared__ uint32_t mb[1024];       // 4 KB: mask bits for 32 rows x 1024 keys
  __shared__ float redm[128], reds[128], rowinv[32];

  // XCD-aware remap: hardware round-robins linear block id across 8 XCDs.
  // Give each XCD 8 whole (b,h) groups so K/V (256 KB/group) stay in its L2.
  int lin = blockIdx.x + 32 * (blockIdx.y + 16 * blockIdx.z);  // 0..2047
  int xcd = lin & 7;
  int slot = lin >> 3;                 // 0..255 within XCD
  int bh = xcd * 8 + (slot >> 5);      // 0..63
  int q0 = (slot & 31) * 32;
  int b = bh >> 4;

  int tid = threadIdx.x, w = tid >> 6, lane = tid & 63, l16 = lane & 15, lg = lane >> 4;

  // stage packed mask (contiguous 4KB)
  ((uint4*)mb)[tid] = ((const uint4*)(mbits + ((size_t)b * 1024 + q0) * 32))[tid];

  // hoist Q fragments (A-layout: row = l16, k = lg*8..+8)
  const bf16_t* Qb = Qh + (size_t)bh * 65536;
  const bf16_t* Kb = Kh + (size_t)bh * 65536;
  bf16x8 qa[2][2];
#pragma unroll
  for (int r = 0; r < 2; r++)
#pragma unroll
    for (int kk = 0; kk < 2; kk++)
      qa[r][kk] = *(const bf16x8*)(Qb + (size_t)(q0 + r * 16 + l16) * 64 + kk * 32 + lg * 8);

  // scores: wave w covers keys [w*256, w*256+256)
  f32x4 zv = {0.f, 0.f, 0.f, 0.f};
  f32x4 sc[2][16];
#pragma unroll
  for (int rt = 0; rt < 2; rt++)
#pragma unroll
    for (int c = 0; c < 16; c++) sc[rt][c] = zv;
  int kcol0 = w * 256;
#pragma unroll 4
  for (int c = 0; c < 16; c++) {
#pragma unroll
    for (int kk = 0; kk < 2; kk++) {
      bf16x8 kv = *(const bf16x8*)(Kb + (size_t)(kcol0 + c * 16 + l16) * 64 + kk * 32 + lg * 8);
      sc[0][c] = mfma16(qa[0][kk], kv, sc[0][c]);
      sc[1][c] = mfma16(qa[1][kk], kv, sc[1][c]);
    }
  }
  __syncthreads();  // mb staged

  // mask + scale + row max (C-layout: row = rt*16 + lg*4 + i, col = kcol0 + c*16 + l16)
  float rmax[2][4], rsum[2][4], rinv[2][4];
#pragma unroll
  for (int rt = 0; rt < 2; rt++)
#pragma unroll
    for (int i = 0; i < 4; i++) rmax[rt][i] = -3e38f;
  const float scale = 0.125f;  // 1/sqrt(64)
#pragma unroll
  for (int rt = 0; rt < 2; rt++) {
#pragma unroll
    for (int j = 0; j < 8; j++) {
      uint32_t wd[4];
#pragma unroll
      for (int i = 0; i < 4; i++) wd[i] = mb[(rt * 16 + lg * 4 + i) * 32 + w * 8 + j];
#pragma unroll
      for (int hf = 0; hf < 2; hf++) {
        int c = j * 2 + hf;
#pragma unroll
        for (int i = 0; i < 4; i++) {
          float s = sc[rt][c][i] * scale;
          if ((wd[i] >> (l16 + hf * 16)) & 1u) s = -1e9f;  // mask==True -> -1e9
          sc[rt][c][i] = s;
          rmax[rt][i] = fmaxf(rmax[rt][i], s);
        }
      }
    }
  }
#pragma unroll
  for (int m = 1; m < 16; m <<= 1)
#pragma unroll
    for (int rt = 0; rt < 2; rt++)
#pragma unroll
      for (int i = 0; i < 4; i++) rmax[rt][i] = fmaxf(rmax[rt][i], __shfl_xor(rmax[rt][i], m));
  if (l16 == 0) {
#pragma unroll
    for (int rt = 0; rt < 2; rt++)
#pragma unroll
      for (int i = 0; i < 4; i++) redm[w * 32 + rt * 16 + lg * 4 + i] = rmax[rt][i];
  }
  __syncthreads();
#pragma unroll
  for (int rt = 0; rt < 2; rt++)
#pragma unroll
    for (int i = 0; i < 4; i++) {
      int row = rt * 16 + lg * 4 + i;
      rmax[rt][i] = fmaxf(fmaxf(redm[row], redm[32 + row]), fmaxf(redm[64 + row], redm[96 + row]));
      rsum[rt][i] = 0.f;
    }
  // exp + row sum
#pragma unroll
  for (int rt = 0; rt < 2; rt++)
#pragma unroll
    for (int c = 0; c < 16; c++)
#pragma unroll
      for (int i = 0; i < 4; i++) {
        float p = __expf(sc[rt][c][i] - rmax[rt][i]);
        sc[rt][c][i] = p;
        rsum[rt][i] += p;
      }
#pragma unroll
  for (int m = 1; m < 16; m <<= 1)
#pragma unroll
    for (int rt = 0; rt < 2; rt++)
#pragma unroll
      for (int i = 0; i < 4; i++) rsum[rt][i] += __shfl_xor(rsum[rt][i], m);
  if (l16 == 0) {
#pragma unroll
    for (int rt = 0; rt < 2; rt++)
#pragma unroll
      for (int i = 0; i < 4; i++) reds[w * 32 + rt * 16 + lg * 4 + i] = rsum[rt][i];
  }
  __syncthreads();
#pragma unroll
  for (int rt = 0; rt < 2; rt++)
#pragma unroll
    for (int i = 0; i < 4; i++) {
      int row = rt * 16 + lg * 4 + i;
      float gs = reds[row] + reds[32 + row] + reds[64 + row] + reds[96 + row];
      rinv[rt][i] = 1.0f / gs;
    }
  // publish per-row 1/sum for the coalesced writer pass
  if (w == 0 && l16 == 0) {
#pragma unroll
    for (int rt = 0; rt < 2; rt++)
#pragma unroll
      for (int i = 0; i < 4; i++) rowinv[rt * 16 + lg * 4 + i] = rinv[rt][i];
  }

  // stash unnormalized P bf16 in LDS (C-fragment scatter is fine in LDS)
#pragma unroll
  for (int rt = 0; rt < 2; rt++)
#pragma unroll
    for (int c = 0; c < 16; c++) {
      int colk = kcol0 + c * 16 + l16;
#pragma unroll
      for (int i = 0; i < 4; i++) {
        int row = rt * 16 + lg * 4 + i;
        P[row * PSTR + colk] = to_bf(sc[rt][c][i]);
      }
    }
  __syncthreads();

  // PV: wave w computes dv tile [w*16, w*16+16) for all 32 rows
  f32x4 oacc0 = zv, oacc1 = zv;
  const bf16_t* Vb = Vt + ((size_t)bh * 64 + w * 16 + l16) * 1024 + lg * 8;
#pragma unroll 4
  for (int ks = 0; ks < 32; ks++) {
    bf16x8 vv = *(const bf16x8*)(Vb + ks * 32);
    bf16x8 a0 = *(const bf16x8*)(P + l16 * PSTR + ks * 32 + lg * 8);
    bf16x8 a1 = *(const bf16x8*)(P + (16 + l16) * PSTR + ks * 32 + lg * 8);
    oacc0 = mfma16(a0, vv, oacc0);
    oacc1 = mfma16(a1, vv, oacc1);
  }

  // coalesced attention write: wave w owns rows [w*8, w*8+8); 1KB contiguous
  // streaming stores (sc0 sc1 nt: no L2 allocate -> no RFO, no K/V eviction)
  float* ob = attn_out + ((size_t)bh * 1024 + q0) * 1024;
#pragma unroll
  for (int rr = 0; rr < 8; rr++) {
    int row = w * 8 + rr;
    float inv = rowinv[row];
#pragma unroll
    for (int c = 0; c < 4; c++) {
      int col = c * 256 + lane * 4;
      bf16x4 p4 = *(const bf16x4*)(P + row * PSTR + col);
      f32x4 o = { (float)p4[0] * inv, (float)p4[1] * inv, (float)p4[2] * inv, (float)p4[3] * inv };
      stream_store16(ob + (size_t)row * 1024 + col, o);
    }
  }

  // ctx write (re-read by out_gemm soon; keep cached)
#pragma unroll
  for (int i = 0; i < 4; i++) {
    int s0r = q0 + lg * 4 + i;
    ctx[((size_t)b * 1024 + s0r) * 1024 + (bh & 15) * 64 + w * 16 + l16] = to_bf(oacc0[i] * rinv[0][i]);
    int s1r = q0 + 16 + lg * 4 + i;
    ctx[((size_t)b * 1024 + s1r) * 1024 + (bh & 15) * 64 + w * 16 + l16] = to_bf(oacc1[i] * rinv[1][i]);
  }
}

// ---------------- output projection GEMM + bias + residual ----------------
__global__ __launch_bounds__(256, 2) void out_gemm_kernel(
    const bf16_t* __restrict__ ctx, const bf16_t* __restrict__ WoT,
    const float* __restrict__ bo, const float* __restrict__ resid, float* __restrict__ preLN) {
  __shared__ bf16_t As[128 * 64], Bs[128 * 64];
  int m0 = blockIdx.y * 128, n0 = blockIdx.x * 128;
  f32x4 acc[4][4];
  gemm128_core(ctx, WoT, m0, n0, As, Bs, acc);
  int tid = threadIdx.x, w = tid >> 6, lane = tid & 63, l16 = lane & 15, lg = lane >> 4;
  int wr = w >> 1, wc = w & 1;
#pragma unroll
  for (int c = 0; c < 4; c++) {
    int col = n0 + wc * 64 + c * 16 + l16;
    float bb = bo[col];
#pragma unroll
    for (int r = 0; r < 4; r++) {
#pragma unroll
      for (int i = 0; i < 4; i++) {
        int mrow = m0 + wr * 64 + r * 16 + lg * 4 + i;
        preLN[(size_t)mrow * 1024 + col] = acc[r][c][i] + bb + resid[(size_t)mrow * 1024 + col];
      }
    }
  }
}

// ---------------- rowwise LayerNorm ----------------
__global__ void ln_kernel(const float* __restrict__ pre, float* __restrict__ out) {
  int row = blockIdx.x, tid = threadIdx.x;  // 256 threads, 4 floats each
  const f32x4 v = ((const f32x4*)(pre + (size_t)row * 1024))[tid];
  float s = v[0] + v[1] + v[2] + v[3];
  float s2 = v[0] * v[0] + v[1] * v[1] + v[2] * v[2] + v[3] * v[3];
#pragma unroll
  for (int m = 32; m > 0; m >>= 1) { s += __shfl_xor(s, m); s2 += __shfl_xor(s2, m); }
  __shared__ float rs[4], rs2[4];
  int w = tid >> 6;
  if ((tid & 63) == 0) { rs[w] = s; rs2[w] = s2; }
  __syncthreads();
  float S = rs[0] + rs[1] + rs[2] + rs[3];
  float S2 = rs2[0] + rs2[1] + rs2[2] + rs2[3];
  float mu = S * (1.f / 1024.f);
  float var = S2 * (1.f / 1024.f) - mu * mu;
  float rstd = rsqrtf(var + 1e-5f);
  f32x4 o = { (v[0] - mu) * rstd, (v[1] - mu) * rstd, (v[2] - mu) * rstd, (v[3] - mu) * rstd };
  ((f32x4*)(out + (size_t)row * 1024))[tid] = o;
}

extern "C" void kernel_launch(void* const* d_in, const int* in_sizes, int n_in,
                              void* d_out, int out_size, void* d_ws, size_t ws_size,
                              hipStream_t stream) {
  const float* q  = (const float*)d_in[0];
  const float* k  = (const float*)d_in[1];
  const float* v  = (const float*)d_in[2];
  const uint8_t* mask = (const uint8_t*)d_in[3];  // numpy bool_, 1 byte/elem
  const float* Wq = (const float*)d_in[4];
  const float* bq = (const float*)d_in[5];
  const float* Wk = (const float*)d_in[6];
  const float* bk = (const float*)d_in[7];
  const float* Wv = (const float*)d_in[8];
  const float* bv = (const float*)d_in[9];
  const float* Wo = (const float*)d_in[10];
  const float* bo = (const float*)d_in[11];

  char* wsp = (char*)d_ws;
  size_t off = 0;
  auto carve = [&](size_t bytes) { void* p = wsp + off; off += (bytes + 255) & ~(size_t)255; return p; };
  bf16_t* qb  = (bf16_t*)carve((size_t)NTOK * 1024 * 2);
  bf16_t* kb  = (bf16_t*)carve((size_t)NTOK * 1024 * 2);
  bf16_t* vb  = (bf16_t*)carve((size_t)NTOK * 1024 * 2);
  bf16_t* WqT = (bf16_t*)carve((size_t)1024 * 1024 * 2);
  bf16_t* WkT = (bf16_t*)carve((size_t)1024 * 1024 * 2);
  bf16_t* WvT = (bf16_t*)carve((size_t)1024 * 1024 * 2);
  bf16_t* WoT = (bf16_t*)carve((size_t)1024 * 1024 * 2);
  bf16_t* Qh  = (bf16_t*)carve((size_t)NTOK * 1024 * 2);
  bf16_t* Kh  = (bf16_t*)carve((size_t)NTOK * 1024 * 2);
  bf16_t* Vh  = (bf16_t*)carve((size_t)NTOK * 1024 * 2);
  bf16_t* Vt  = (bf16_t*)carve((size_t)NTOK * 1024 * 2);
  bf16_t* ctx = (bf16_t*)carve((size_t)NTOK * 1024 * 2);
  uint32_t* mbits = (uint32_t*)carve((size_t)B_ * S_ * 32 * 4);  // 512 KB
  float* preLN = (float*)carve((size_t)NTOK * 1024 * 4);
  (void)ws_size; (void)in_sizes; (void)n_in; (void)out_size;

  float* lnout = (float*)d_out;                          // [B,S,D] fp32
  float* attn_out = (float*)d_out + (size_t)NTOK * 1024; // [B,H,S,S] fp32

  cvt3_kernel<<<dim3(4096, 1, 3), 256, 0, stream>>>(q, k, v, qb, kb, vb);
  wT4_kernel<<<dim3(32, 32, 4), dim3(32, 8), 0, stream>>>(Wq, Wk, Wv, Wo, WqT, WkT, WvT, WoT);
  maskpack_kernel<<<512, 256, 0, stream>>>((const uint32_t*)mask, mbits);
  qkv_gemm_kernel<<<dim3(8, 32, 3), 256, 0, stream>>>(qb, kb, vb, WqT, WkT, WvT,
                                                      bq, bk, bv, Qh, Kh, Vh);
  vT_kernel<<<dim3(16, 16, 4), 256, 0, stream>>>(Vh, Vt);
  attn_kernel<<<dim3(32, 16, 4), 256, 0, stream>>>(Qh, Kh, Vt, mbits, attn_out, ctx);
  out_gemm_kernel<<<dim3(8, 32), 256, 0, stream>>>(ctx, WoT, bo, q, preLN);
  ln_kernel<<<4096, 256, 0, stream>>>(preLN, lnout);
}